// Round 1
// baseline (4071.786 us; speedup 1.0000x reference)
//
#include <hip/hip_runtime.h>
#include <math.h>

// ---- problem constants ----
#define B_TOT   2048
#define H_STEPS 64
#define A_DIM   32
#define S_DIM   32
#define D_DIM   200
#define HID_DIM 200
#define XDIM    64          // S + A
#define G3      600         // 3*D
#define OUT_FEAT 296        // D + 3*S
#define BT      8           // batch elements per block

// ---- workspace layout (floats): transposed weights [k][o] ----
#define OFF_WTIH 0                                   // [64][600]
#define OFF_WTHH (OFF_WTIH + XDIM * G3)              // 38400  : [200][600]
#define OFF_WT1  (OFF_WTHH + D_DIM * G3)             // 158400 : [200][200]
#define OFF_WT2  (OFF_WT1 + HID_DIM * HID_DIM)       // 198400 : [200][200]
#define OFF_WTMS (OFF_WT2 + HID_DIM * HID_DIM)       // 238400 : [200][64] (Wm^T | Ws^T)
#define WS_FLOATS (OFF_WTMS + HID_DIM * 64)          // 251200

// -------- setup: transpose weights into coalesced-on-output layout --------
__global__ void transpose_weights(const float* __restrict__ W_ih,
                                  const float* __restrict__ W_hh,
                                  const float* __restrict__ W1,
                                  const float* __restrict__ W2,
                                  const float* __restrict__ Wm,
                                  const float* __restrict__ Ws,
                                  float* __restrict__ ws)
{
    int i = blockIdx.x * 256 + threadIdx.x;
    if (i < OFF_WTHH) {                         // WT_ih [64][600]
        int k = i / G3, o = i % G3;
        ws[i] = W_ih[o * XDIM + k];
    } else if (i < OFF_WT1) {                   // WT_hh [200][600]
        int j = i - OFF_WTHH; int k = j / G3, o = j % G3;
        ws[i] = W_hh[o * D_DIM + k];
    } else if (i < OFF_WT2) {                   // WT1 [200][200]
        int j = i - OFF_WT1; int k = j / HID_DIM, o = j % HID_DIM;
        ws[i] = W1[o * D_DIM + k];
    } else if (i < OFF_WTMS) {                  // WT2 [200][200]
        int j = i - OFF_WT2; int k = j / HID_DIM, o = j % HID_DIM;
        ws[i] = W2[o * HID_DIM + k];
    } else if (i < WS_FLOATS) {                 // WTms [200][64]
        int j = i - OFF_WTMS; int k = j / 64, o = j % 64;
        ws[i] = (o < 32) ? Wm[o * HID_DIM + k] : Ws[(o - 32) * HID_DIM + k];
    }
}

__device__ __forceinline__ float sigmoid_f(float x) {
    return 1.0f / (1.0f + __expf(-x));
}

// -------- main rollout kernel: one block = BT batch elements, all 64 steps --------
__global__ __launch_bounds__(256) void rssm_rollout(
    const float* __restrict__ h0, const float* __restrict__ z0,
    const float* __restrict__ actions, const float* __restrict__ eps,
    const float* __restrict__ b_ih, const float* __restrict__ b_hh,
    const float* __restrict__ b1, const float* __restrict__ b2,
    const float* __restrict__ bm, const float* __restrict__ bs,
    const float* __restrict__ ws, float* __restrict__ out)
{
    __shared__ __align__(16) float x_lds[XDIM][BT];     // concat(z, a), [k][b]
    __shared__ __align__(16) float hA[D_DIM][BT];
    __shared__ __align__(16) float hB[D_DIM][BT];
    __shared__ __align__(16) float f1_lds[HID_DIM][BT];
    __shared__ __align__(16) float f2_lds[HID_DIM][BT];
    __shared__ __align__(16) float ms_lds[2][S_DIM][BT]; // mean, std

    const int t  = threadIdx.x;
    const int b0 = blockIdx.x * BT;

    const float* WT_ih = ws + OFF_WTIH;
    const float* WT_hh = ws + OFF_WTHH;
    const float* WT1   = ws + OFF_WT1;
    const float* WT2   = ws + OFF_WT2;
    const float* WTms  = ws + OFF_WTMS;

    // init state: h0 -> hA, z0 -> x_lds[0..31]
    for (int idx = t; idx < D_DIM * BT; idx += 256) {
        int k = idx >> 3, b = idx & 7;
        hA[k][b] = h0[(b0 + b) * D_DIM + k];
    }
    for (int idx = t; idx < S_DIM * BT; idx += 256) {
        int k = idx >> 3, b = idx & 7;
        x_lds[k][b] = z0[(b0 + b) * S_DIM + k];
    }

    float* hcur = &hA[0][0];
    float* hnxt = &hB[0][0];

    for (int step = 0; step < H_STEPS; ++step) {
        // load this step's actions into x_lds[32+j][b] (all 256 threads)
        {
            int b = t >> 5, j = t & 31;
            x_lds[S_DIM + j][b] = actions[((b0 + b) * H_STEPS + step) * A_DIM + j];
        }
        __syncthreads();   // B1: x, h ready

        // ---- GRU gates: thread t owns feature t (r, u, n fused) ----
        if (t < D_DIM) {
            float ar[BT], au[BT], ain[BT], ahn[BT];
            #pragma unroll
            for (int b = 0; b < BT; ++b) { ar[b] = 0.f; au[b] = 0.f; ain[b] = 0.f; ahn[b] = 0.f; }

            const float4* xv = (const float4*)&x_lds[0][0];
            #pragma unroll 4
            for (int k = 0; k < XDIM; ++k) {
                float wr = WT_ih[k * G3 + t];
                float wu = WT_ih[k * G3 + t + 200];
                float wn = WT_ih[k * G3 + t + 400];
                float4 v0 = xv[k * 2], v1 = xv[k * 2 + 1];
                float xs[BT] = {v0.x, v0.y, v0.z, v0.w, v1.x, v1.y, v1.z, v1.w};
                #pragma unroll
                for (int b = 0; b < BT; ++b) {
                    ar[b]  += wr * xs[b];
                    au[b]  += wu * xs[b];
                    ain[b] += wn * xs[b];
                }
            }
            const float4* hv = (const float4*)hcur;
            #pragma unroll 2
            for (int k = 0; k < D_DIM; ++k) {
                float wr = WT_hh[k * G3 + t];
                float wu = WT_hh[k * G3 + t + 200];
                float wn = WT_hh[k * G3 + t + 400];
                float4 v0 = hv[k * 2], v1 = hv[k * 2 + 1];
                float hs[BT] = {v0.x, v0.y, v0.z, v0.w, v1.x, v1.y, v1.z, v1.w};
                #pragma unroll
                for (int b = 0; b < BT; ++b) {
                    ar[b]  += wr * hs[b];
                    au[b]  += wu * hs[b];
                    ahn[b] += wn * hs[b];
                }
            }
            const float brz = b_ih[t]       + b_hh[t];
            const float buz = b_ih[t + 200] + b_hh[t + 200];
            const float bin = b_ih[t + 400];
            const float bhn = b_hh[t + 400];
            float* hrow_c = hcur + t * BT;
            float* hrow_n = hnxt + t * BT;
            #pragma unroll
            for (int b = 0; b < BT; ++b) {
                float r  = sigmoid_f(ar[b] + brz);
                float u  = sigmoid_f(au[b] + buz);
                float n  = tanhf(ain[b] + bin + r * (ahn[b] + bhn));
                float hn = (1.0f - u) * n + u * hrow_c[b];
                hrow_n[b] = hn;
                out[((b0 + b) * H_STEPS + step) * OUT_FEAT + t] = hn;
            }
        }
        __syncthreads();   // B2: h_new ready

        // ---- f1 = elu(h_new @ W1^T + b1) ----
        if (t < HID_DIM) {
            float acc[BT];
            #pragma unroll
            for (int b = 0; b < BT; ++b) acc[b] = 0.f;
            const float4* hv = (const float4*)hnxt;
            #pragma unroll 2
            for (int k = 0; k < D_DIM; ++k) {
                float w = WT1[k * HID_DIM + t];
                float4 v0 = hv[k * 2], v1 = hv[k * 2 + 1];
                float hs[BT] = {v0.x, v0.y, v0.z, v0.w, v1.x, v1.y, v1.z, v1.w};
                #pragma unroll
                for (int b = 0; b < BT; ++b) acc[b] += w * hs[b];
            }
            float bb = b1[t];
            #pragma unroll
            for (int b = 0; b < BT; ++b) {
                float v = acc[b] + bb;
                f1_lds[t][b] = (v > 0.f) ? v : (__expf(v) - 1.0f);
            }
        }
        __syncthreads();   // B3: f1 ready

        // ---- f2 = elu(f1 @ W2^T + b2) ----
        if (t < HID_DIM) {
            float acc[BT];
            #pragma unroll
            for (int b = 0; b < BT; ++b) acc[b] = 0.f;
            const float4* fv = (const float4*)&f1_lds[0][0];
            #pragma unroll 2
            for (int k = 0; k < HID_DIM; ++k) {
                float w = WT2[k * HID_DIM + t];
                float4 v0 = fv[k * 2], v1 = fv[k * 2 + 1];
                float hs[BT] = {v0.x, v0.y, v0.z, v0.w, v1.x, v1.y, v1.z, v1.w};
                #pragma unroll
                for (int b = 0; b < BT; ++b) acc[b] += w * hs[b];
            }
            float bb = b2[t];
            #pragma unroll
            for (int b = 0; b < BT; ++b) {
                float v = acc[b] + bb;
                f2_lds[t][b] = (v > 0.f) ? v : (__expf(v) - 1.0f);
            }
        }
        __syncthreads();   // B4: f2 ready

        // ---- heads: mean (t<32), logstd->std (32<=t<64) ----
        if (t < 64) {
            float acc[BT];
            #pragma unroll
            for (int b = 0; b < BT; ++b) acc[b] = 0.f;
            const float4* fv = (const float4*)&f2_lds[0][0];
            #pragma unroll 2
            for (int k = 0; k < HID_DIM; ++k) {
                float w = WTms[k * 64 + t];
                float4 v0 = fv[k * 2], v1 = fv[k * 2 + 1];
                float hs[BT] = {v0.x, v0.y, v0.z, v0.w, v1.x, v1.y, v1.z, v1.w};
                #pragma unroll
                for (int b = 0; b < BT; ++b) acc[b] += w * hs[b];
            }
            if (t < S_DIM) {
                float bb = bm[t];
                #pragma unroll
                for (int b = 0; b < BT; ++b)
                    ms_lds[0][t][b] = acc[b] + bb;
            } else {
                float bb = bs[t - 32];
                #pragma unroll
                for (int b = 0; b < BT; ++b) {
                    float ls = acc[b] + bb;
                    ls = fminf(fmaxf(ls, -10.0f), 2.0f);
                    ms_lds[1][t - 32][b] = __expf(ls);
                }
            }
        }
        __syncthreads();   // B5: mean/std ready

        // ---- reparameterized sample + outputs ----
        if (t < S_DIM) {
            #pragma unroll
            for (int b = 0; b < BT; ++b) {
                float mean = ms_lds[0][t][b];
                float stdv = ms_lds[1][t][b];
                float e = eps[((b0 + b) * H_STEPS + step) * S_DIM + t];
                float z = mean + stdv * e;
                x_lds[t][b] = z;   // becomes next step's input
                int base = ((b0 + b) * H_STEPS + step) * OUT_FEAT;
                out[base + D_DIM + t]             = z;
                out[base + D_DIM + S_DIM + t]     = mean;
                out[base + D_DIM + 2 * S_DIM + t] = stdv;
            }
        }
        // swap h buffers; top-of-loop B1 covers the x_lds z-writes
        float* tmp = hcur; hcur = hnxt; hnxt = tmp;
    }
}

extern "C" void kernel_launch(void* const* d_in, const int* in_sizes, int n_in,
                              void* d_out, int out_size, void* d_ws, size_t ws_size,
                              hipStream_t stream) {
    const float* h0      = (const float*)d_in[0];
    const float* z0      = (const float*)d_in[1];
    const float* actions = (const float*)d_in[2];
    const float* eps     = (const float*)d_in[3];
    const float* W_ih    = (const float*)d_in[4];
    const float* b_ih    = (const float*)d_in[5];
    const float* W_hh    = (const float*)d_in[6];
    const float* b_hh    = (const float*)d_in[7];
    const float* W1      = (const float*)d_in[8];
    const float* b1      = (const float*)d_in[9];
    const float* W2      = (const float*)d_in[10];
    const float* b2      = (const float*)d_in[11];
    const float* Wm      = (const float*)d_in[12];
    const float* bm      = (const float*)d_in[13];
    const float* Ws      = (const float*)d_in[14];
    const float* bs      = (const float*)d_in[15];

    float* ws = (float*)d_ws;
    float* out = (float*)d_out;

    // transpose weights into workspace (runs every launch; graph-safe)
    hipLaunchKernelGGL(transpose_weights, dim3((WS_FLOATS + 255) / 256), dim3(256), 0, stream,
                       W_ih, W_hh, W1, W2, Wm, Ws, ws);

    // main rollout: 256 blocks x 256 threads, BT=8 batch rows per block
    hipLaunchKernelGGL(rssm_rollout, dim3(B_TOT / BT), dim3(256), 0, stream,
                       h0, z0, actions, eps, b_ih, b_hh, b1, b2, bm, bs, ws, out);
}

// Round 2
// 3238.601 us; speedup vs baseline: 1.2573x; 1.2573x over previous
//
#include <hip/hip_runtime.h>
#include <math.h>

// ---- problem constants ----
#define B_TOT   2048
#define H_STEPS 64
#define A_DIM   32
#define S_DIM   32
#define D_DIM   200
#define HID_DIM 200
#define XDIM    64          // S + A
#define KTOT    264         // XDIM + D (combined GRU reduction dim)
#define OUT_FEAT 296        // D + 3*S
#define BT      4           // batch elements per block -> grid 512 = 2 blocks/CU

// ---- workspace layout (uint32 units): bf16-packed transposed weights ----
// WRU  [264][200] : (w_r, w_u) pair for combined k (k<64: W_ih cols, else W_hh)
// WN   [132][200] : (w_n[2k], w_n[2k+1]) k-pairs, combined k
// W1P  [100][200] : (W1[t][2k], W1[t][2k+1])
// W2P  [100][200]
// WMSP [100][64]  : heads, o<32 = Wm row, o>=32 = Ws row
#define OFF_WRU 0
#define OFF_WN  (KTOT * 200)             // 52800
#define OFF_W1P (OFF_WN + 132 * 200)     // 79200
#define OFF_W2P (OFF_W1P + 100 * 200)    // 99200
#define OFF_WMS (OFF_W2P + 100 * 200)    // 119200
#define WS_U32  (OFF_WMS + 100 * 64)     // 125600 u32 = 502.4 KB

__device__ __forceinline__ unsigned pack_bf16(float a, float b) {
    unsigned ua = __float_as_uint(a), ub = __float_as_uint(b);
    ua = (ua + 0x7fffu + ((ua >> 16) & 1u)) >> 16;   // RNE
    ub = (ub + 0x7fffu + ((ub >> 16) & 1u)) >> 16;
    return ua | (ub << 16);
}

__global__ void pack_weights(const float* __restrict__ W_ih,
                             const float* __restrict__ W_hh,
                             const float* __restrict__ W1,
                             const float* __restrict__ W2,
                             const float* __restrict__ Wm,
                             const float* __restrict__ Ws,
                             unsigned* __restrict__ ws)
{
    int i = blockIdx.x * 256 + threadIdx.x;
    if (i >= WS_U32) return;
    if (i < OFF_WN) {                                  // WRU
        int k = i / 200, t = i % 200;
        float wr, wu;
        if (k < XDIM) { wr = W_ih[t * XDIM + k];        wu = W_ih[(200 + t) * XDIM + k]; }
        else { int kk = k - XDIM; wr = W_hh[t * 200 + kk]; wu = W_hh[(200 + t) * 200 + kk]; }
        ws[i] = pack_bf16(wr, wu);
    } else if (i < OFF_W1P) {                          // WN (k-pairs never straddle 64)
        int j = i - OFF_WN; int kp = j / 200, t = j % 200;
        int k0 = 2 * kp, k1 = 2 * kp + 1;
        float w0 = (k0 < XDIM) ? W_ih[(400 + t) * XDIM + k0] : W_hh[(400 + t) * 200 + (k0 - XDIM)];
        float w1 = (k1 < XDIM) ? W_ih[(400 + t) * XDIM + k1] : W_hh[(400 + t) * 200 + (k1 - XDIM)];
        ws[i] = pack_bf16(w0, w1);
    } else if (i < OFF_W2P) {                          // W1P
        int j = i - OFF_W1P; int kp = j / 200, t = j % 200;
        ws[i] = pack_bf16(W1[t * 200 + 2 * kp], W1[t * 200 + 2 * kp + 1]);
    } else if (i < OFF_WMS) {                          // W2P
        int j = i - OFF_W2P; int kp = j / 200, t = j % 200;
        ws[i] = pack_bf16(W2[t * 200 + 2 * kp], W2[t * 200 + 2 * kp + 1]);
    } else {                                           // WMSP
        int j = i - OFF_WMS; int kp = j / 64, o = j % 64;
        const float* src = (o < 32) ? (Wm + o * 200) : (Ws + (o - 32) * 200);
        ws[i] = pack_bf16(src[2 * kp], src[2 * kp + 1]);
    }
}

__device__ __forceinline__ float sigmoid_f(float x) {
    return 1.0f / (1.0f + __expf(-x));
}
__device__ __forceinline__ float unpack_lo(unsigned w) { return __uint_as_float(w << 16); }
__device__ __forceinline__ float unpack_hi(unsigned w) { return __uint_as_float(w & 0xffff0000u); }

// -------- main rollout: one block = 4 batch rows, all 64 steps, 4 barriers/step --------
__global__ __launch_bounds__(256) void rssm_rollout(
    const float* __restrict__ h0, const float* __restrict__ z0,
    const float* __restrict__ actions, const float* __restrict__ eps,
    const float* __restrict__ b_ih, const float* __restrict__ b_hh,
    const float* __restrict__ b1, const float* __restrict__ b2,
    const float* __restrict__ bm, const float* __restrict__ bs,
    const unsigned* __restrict__ wsu, float* __restrict__ out)
{
    __shared__ __align__(16) float4 xh4[KTOT];     // [z(32) | a(32) | h(200)] x 4 batch
    __shared__ __align__(16) float4 hnew4[D_DIM];
    __shared__ __align__(16) float4 f1v[HID_DIM];
    __shared__ __align__(16) float4 f2v[HID_DIM];
    float* xh_f = (float*)xh4;

    const int t  = threadIdx.x;
    const int b0 = blockIdx.x * BT;

    // init: h0 -> xh[64..263], z0 -> xh[0..31]
    for (int idx = t; idx < D_DIM * BT; idx += 256) {
        int k = idx >> 2, b = idx & 3;
        xh_f[(XDIM + k) * 4 + b] = h0[(b0 + b) * D_DIM + k];
    }
    for (int idx = t; idx < S_DIM * BT; idx += 256) {
        int k = idx >> 2, b = idx & 3;
        xh_f[k * 4 + b] = z0[(b0 + b) * S_DIM + k];
    }

    for (int step = 0; step < H_STEPS; ++step) {
        // load this step's actions -> xh[32..63]
        if (t < 128) {
            int b = t >> 5, j = t & 31;
            xh_f[(S_DIM + j) * 4 + b] = actions[((b0 + b) * H_STEPS + step) * A_DIM + j];
        }
        __syncthreads();   // B1: xh (z, a, h) ready

        // ---- GRU: thread t owns feature t; combined k over [z,a,h] ----
        if (t < D_DIM) {
            float ar[BT]  = {0.f, 0.f, 0.f, 0.f};
            float au[BT]  = {0.f, 0.f, 0.f, 0.f};
            float anx[BT] = {0.f, 0.f, 0.f, 0.f};   // n-gate, x part
            float anh[BT] = {0.f, 0.f, 0.f, 0.f};   // n-gate, h part
            const unsigned* WRU = wsu + OFF_WRU;
            const unsigned* WN  = wsu + OFF_WN;

            #pragma unroll 4
            for (int kp = 0; kp < 32; ++kp) {        // x part (k = 0..63)
                unsigned ru0 = WRU[(2 * kp) * 200 + t];
                unsigned ru1 = WRU[(2 * kp + 1) * 200 + t];
                unsigned nn  = WN[kp * 200 + t];
                float4 v0 = xh4[2 * kp], v1 = xh4[2 * kp + 1];
                float x0[BT] = {v0.x, v0.y, v0.z, v0.w};
                float x1[BT] = {v1.x, v1.y, v1.z, v1.w};
                float wr0 = unpack_lo(ru0), wu0 = unpack_hi(ru0);
                float wr1 = unpack_lo(ru1), wu1 = unpack_hi(ru1);
                float wn0 = unpack_lo(nn),  wn1 = unpack_hi(nn);
                #pragma unroll
                for (int b = 0; b < BT; ++b) {
                    ar[b]  += wr0 * x0[b] + wr1 * x1[b];
                    au[b]  += wu0 * x0[b] + wu1 * x1[b];
                    anx[b] += wn0 * x0[b] + wn1 * x1[b];
                }
            }
            #pragma unroll 4
            for (int kp = 32; kp < 132; ++kp) {      // h part (k = 64..263)
                unsigned ru0 = WRU[(2 * kp) * 200 + t];
                unsigned ru1 = WRU[(2 * kp + 1) * 200 + t];
                unsigned nn  = WN[kp * 200 + t];
                float4 v0 = xh4[2 * kp], v1 = xh4[2 * kp + 1];
                float x0[BT] = {v0.x, v0.y, v0.z, v0.w};
                float x1[BT] = {v1.x, v1.y, v1.z, v1.w};
                float wr0 = unpack_lo(ru0), wu0 = unpack_hi(ru0);
                float wr1 = unpack_lo(ru1), wu1 = unpack_hi(ru1);
                float wn0 = unpack_lo(nn),  wn1 = unpack_hi(nn);
                #pragma unroll
                for (int b = 0; b < BT; ++b) {
                    ar[b]  += wr0 * x0[b] + wr1 * x1[b];
                    au[b]  += wu0 * x0[b] + wu1 * x1[b];
                    anh[b] += wn0 * x0[b] + wn1 * x1[b];
                }
            }
            const float brz = b_ih[t] + b_hh[t];
            const float buz = b_ih[t + 200] + b_hh[t + 200];
            const float bin = b_ih[t + 400];
            const float bhn = b_hh[t + 400];
            float4 hold = xh4[XDIM + t];
            float ho[BT] = {hold.x, hold.y, hold.z, hold.w};
            float hn[BT];
            #pragma unroll
            for (int b = 0; b < BT; ++b) {
                float r = sigmoid_f(ar[b] + brz);
                float u = sigmoid_f(au[b] + buz);
                float n = tanhf(anx[b] + bin + r * (anh[b] + bhn));
                hn[b] = (1.0f - u) * n + u * ho[b];
                out[((b0 + b) * H_STEPS + step) * OUT_FEAT + t] = hn[b];
            }
            hnew4[t] = make_float4(hn[0], hn[1], hn[2], hn[3]);
        }
        __syncthreads();   // B2: h_new ready

        // ---- f1 = elu(h_new @ W1^T + b1) ----
        if (t < HID_DIM) {
            float acc[BT] = {0.f, 0.f, 0.f, 0.f};
            const unsigned* W1P = wsu + OFF_W1P;
            #pragma unroll 4
            for (int kp = 0; kp < 100; ++kp) {
                unsigned w = W1P[kp * 200 + t];
                float4 v0 = hnew4[2 * kp], v1 = hnew4[2 * kp + 1];
                float lo = unpack_lo(w), hi = unpack_hi(w);
                float x0[BT] = {v0.x, v0.y, v0.z, v0.w};
                float x1[BT] = {v1.x, v1.y, v1.z, v1.w};
                #pragma unroll
                for (int b = 0; b < BT; ++b) acc[b] += lo * x0[b] + hi * x1[b];
            }
            float bb = b1[t], r[BT];
            #pragma unroll
            for (int b = 0; b < BT; ++b) {
                float v = acc[b] + bb;
                r[b] = (v > 0.f) ? v : (__expf(v) - 1.0f);
            }
            f1v[t] = make_float4(r[0], r[1], r[2], r[3]);
        }
        __syncthreads();   // B3: f1 ready

        // ---- f2 = elu(f1 @ W2^T + b2) ----
        if (t < HID_DIM) {
            float acc[BT] = {0.f, 0.f, 0.f, 0.f};
            const unsigned* W2P = wsu + OFF_W2P;
            #pragma unroll 4
            for (int kp = 0; kp < 100; ++kp) {
                unsigned w = W2P[kp * 200 + t];
                float4 v0 = f1v[2 * kp], v1 = f1v[2 * kp + 1];
                float lo = unpack_lo(w), hi = unpack_hi(w);
                float x0[BT] = {v0.x, v0.y, v0.z, v0.w};
                float x1[BT] = {v1.x, v1.y, v1.z, v1.w};
                #pragma unroll
                for (int b = 0; b < BT; ++b) acc[b] += lo * x0[b] + hi * x1[b];
            }
            float bb = b2[t], r[BT];
            #pragma unroll
            for (int b = 0; b < BT; ++b) {
                float v = acc[b] + bb;
                r[b] = (v > 0.f) ? v : (__expf(v) - 1.0f);
            }
            f2v[t] = make_float4(r[0], r[1], r[2], r[3]);
        }
        __syncthreads();   // B4: f2 ready

        // ---- wave0: heads + shfl exchange + sample; waves1-3: h_new -> xh copy ----
        if (t < 64) {
            float acc[BT] = {0.f, 0.f, 0.f, 0.f};
            const unsigned* WMS = wsu + OFF_WMS;
            #pragma unroll 4
            for (int kp = 0; kp < 100; ++kp) {
                unsigned w = WMS[kp * 64 + t];
                float4 v0 = f2v[2 * kp], v1 = f2v[2 * kp + 1];
                float lo = unpack_lo(w), hi = unpack_hi(w);
                float x0[BT] = {v0.x, v0.y, v0.z, v0.w};
                float x1[BT] = {v1.x, v1.y, v1.z, v1.w};
                #pragma unroll
                for (int b = 0; b < BT; ++b) acc[b] += lo * x0[b] + hi * x1[b];
            }
            float v[BT];
            if (t < S_DIM) {
                float bb = bm[t];
                #pragma unroll
                for (int b = 0; b < BT; ++b) v[b] = acc[b] + bb;      // mean
            } else {
                float bb = bs[t - 32];
                #pragma unroll
                for (int b = 0; b < BT; ++b) {
                    float ls = acc[b] + bb;
                    ls = fminf(fmaxf(ls, -10.0f), 2.0f);
                    v[b] = __expf(ls);                                 // std
                }
            }
            float sv[BT];
            #pragma unroll
            for (int b = 0; b < BT; ++b) sv[b] = __shfl(v[b], (t & 31) + 32, 64);
            if (t < S_DIM) {          // lanes 0..31: v=mean, sv=std -> sample
                #pragma unroll
                for (int b = 0; b < BT; ++b) {
                    float e = eps[((b0 + b) * H_STEPS + step) * S_DIM + t];
                    float z = v[b] + sv[b] * e;
                    xh_f[t * 4 + b] = z;                               // next step's z
                    int base = ((b0 + b) * H_STEPS + step) * OUT_FEAT;
                    out[base + D_DIM + t]         = z;
                    out[base + D_DIM + S_DIM + t] = v[b];
                }
            } else {                  // lanes 32..63: write std
                #pragma unroll
                for (int b = 0; b < BT; ++b) {
                    int base = ((b0 + b) * H_STEPS + step) * OUT_FEAT;
                    out[base + D_DIM + 2 * S_DIM + (t - 32)] = v[b];
                }
            }
        } else {
            // waves 1-3 (192 threads): update xh h-section for next step
            for (int k = t - 64; k < D_DIM; k += 192) xh4[XDIM + k] = hnew4[k];
        }
        // loop; B1 at top of next iteration covers all xh writes
    }
}

extern "C" void kernel_launch(void* const* d_in, const int* in_sizes, int n_in,
                              void* d_out, int out_size, void* d_ws, size_t ws_size,
                              hipStream_t stream) {
    const float* h0      = (const float*)d_in[0];
    const float* z0      = (const float*)d_in[1];
    const float* actions = (const float*)d_in[2];
    const float* eps     = (const float*)d_in[3];
    const float* W_ih    = (const float*)d_in[4];
    const float* b_ih    = (const float*)d_in[5];
    const float* W_hh    = (const float*)d_in[6];
    const float* b_hh    = (const float*)d_in[7];
    const float* W1      = (const float*)d_in[8];
    const float* b1      = (const float*)d_in[9];
    const float* W2      = (const float*)d_in[10];
    const float* b2      = (const float*)d_in[11];
    const float* Wm      = (const float*)d_in[12];
    const float* bm      = (const float*)d_in[13];
    const float* Ws      = (const float*)d_in[14];
    const float* bs      = (const float*)d_in[15];

    unsigned* ws = (unsigned*)d_ws;
    float* out = (float*)d_out;

    hipLaunchKernelGGL(pack_weights, dim3((WS_U32 + 255) / 256), dim3(256), 0, stream,
                       W_ih, W_hh, W1, W2, Wm, Ws, ws);

    hipLaunchKernelGGL(rssm_rollout, dim3(B_TOT / BT), dim3(256), 0, stream,
                       h0, z0, actions, eps, b_ih, b_hh, b1, b2, bm, bs, ws, out);
}

// Round 3
// 1802.840 us; speedup vs baseline: 2.2585x; 1.7964x over previous
//
#include <hip/hip_runtime.h>
#include <math.h>

// ---- problem constants ----
#define B_TOT   2048
#define H_STEPS 64
#define A_DIM   32
#define S_DIM   32
#define D_DIM   200
#define OUT_FEAT 296
#define BT      4            // batch rows per block -> grid 512 = 2 blocks/CU

// ---- workspace layout (dword offsets): f16-pair-packed weights ----
// RUN4 uint4[66*200] : per k-group g (k=4g..4g+3): (Rpk(2g),Rpk(2g+1),Upk(2g),Upk(2g+1))
// N2   uint2[66*200] : (Npk(2g),Npk(2g+1))
// W1P  uint2[50*200], W2P uint2[50*200], MS2 uint2[50*64]
#define OFF_RUN4 0
#define OFF_N2   52800
#define OFF_W1   79200
#define OFF_W2   99200
#define OFF_MS   119200
#define WS_DW    125600

typedef _Float16 half2_t __attribute__((ext_vector_type(2)));

__device__ __forceinline__ unsigned pack_h2(float a, float b) {
    union { _Float16 h[2]; unsigned u; } v;
    v.h[0] = (_Float16)a; v.h[1] = (_Float16)b;
    return v.u;
}
__device__ __forceinline__ unsigned f2u16(float x) {
    union { _Float16 h[2]; unsigned u; } v;
    v.u = 0; v.h[0] = (_Float16)x;
    return v.u;
}
__device__ __forceinline__ float dot2f(unsigned w, unsigned x, float c) {
    union { unsigned u; half2_t h; } a, b;
    a.u = w; b.u = x;
#if __has_builtin(__builtin_amdgcn_fdot2)
    return __builtin_amdgcn_fdot2(a.h, b.h, c, false);
#else
    return c + (float)a.h[0] * (float)b.h[0] + (float)a.h[1] * (float)b.h[1];
#endif
}
__device__ __forceinline__ float fast_rcp(float x) { return __builtin_amdgcn_rcpf(x); }
__device__ __forceinline__ float sigmoid_f(float x) {
    return fast_rcp(1.0f + __expf(-x));
}
__device__ __forceinline__ float tanh_f(float x) {
    // 1 - 2/(1+e^{2x}); safe at both extremes
    return 1.0f - 2.0f * fast_rcp(1.0f + __expf(2.0f * x));
}
// combined-k fetch: k<64 -> W_ih col, else W_hh col (row = gate-row index)
__device__ __forceinline__ float gw(const float* Wih, const float* Whh, int row, int k) {
    return (k < 64) ? Wih[row * 64 + k] : Whh[row * 200 + (k - 64)];
}

__global__ void pack_weights(const float* __restrict__ Wih, const float* __restrict__ Whh,
                             const float* __restrict__ W1, const float* __restrict__ W2,
                             const float* __restrict__ Wm, const float* __restrict__ Ws,
                             unsigned* __restrict__ ws)
{
    int i = blockIdx.x * 256 + threadIdx.x;
    if (i >= WS_DW) return;
    if (i < OFF_N2) {                         // RUN4
        int e = i >> 2, c = i & 3;
        int g = e / 200, t = e % 200;
        int kp = 2 * g + (c & 1);
        int row = (c >> 1) ? (200 + t) : t;   // c<2: r-gate rows, c>=2: u-gate rows
        ws[i] = pack_h2(gw(Wih, Whh, row, 2 * kp), gw(Wih, Whh, row, 2 * kp + 1));
    } else if (i < OFF_W1) {                  // N2
        int j = i - OFF_N2, e = j >> 1, c = j & 1;
        int g = e / 200, t = e % 200, kp = 2 * g + c, row = 400 + t;
        ws[i] = pack_h2(gw(Wih, Whh, row, 2 * kp), gw(Wih, Whh, row, 2 * kp + 1));
    } else if (i < OFF_W2) {                  // W1P
        int j = i - OFF_W1, e = j >> 1, c = j & 1;
        int g = e / 200, t = e % 200, kp = 2 * g + c;
        ws[i] = pack_h2(W1[t * 200 + 2 * kp], W1[t * 200 + 2 * kp + 1]);
    } else if (i < OFF_MS) {                  // W2P
        int j = i - OFF_W2, e = j >> 1, c = j & 1;
        int g = e / 200, t = e % 200, kp = 2 * g + c;
        ws[i] = pack_h2(W2[t * 200 + 2 * kp], W2[t * 200 + 2 * kp + 1]);
    } else {                                  // MS2
        int j = i - OFF_MS, e = j >> 1, c = j & 1;
        int g = e / 64, o = e % 64, kp = 2 * g + c;
        const float* src = (o < 32) ? (Wm + o * 200) : (Ws + (o - 32) * 200);
        ws[i] = pack_h2(src[2 * kp], src[2 * kp + 1]);
    }
}

// pack 4 fp32 (one per batch) into half2 pairs with lane t^1; even lanes store b128
__device__ __forceinline__ void pack_store4(unsigned* dst, int pairidx, int odd,
                                            float v0, float v1, float v2, float v3) {
    unsigned a0 = f2u16(v0), a1 = f2u16(v1), a2 = f2u16(v2), a3 = f2u16(v3);
    unsigned p0 = (unsigned)__shfl_xor((int)a0, 1, 64);
    unsigned p1 = (unsigned)__shfl_xor((int)a1, 1, 64);
    unsigned p2 = (unsigned)__shfl_xor((int)a2, 1, 64);
    unsigned p3 = (unsigned)__shfl_xor((int)a3, 1, 64);
    if (!odd) {
        uint4 w;
        w.x = a0 | (p0 << 16); w.y = a1 | (p1 << 16);
        w.z = a2 | (p2 << 16); w.w = a3 | (p3 << 16);
        ((uint4*)dst)[pairidx] = w;
    }
}

__global__ __launch_bounds__(256) void rssm_rollout(
    const float* __restrict__ h0, const float* __restrict__ z0,
    const float* __restrict__ actions, const float* __restrict__ eps,
    const float* __restrict__ b_ih, const float* __restrict__ b_hh,
    const float* __restrict__ b1, const float* __restrict__ b2,
    const float* __restrict__ bm, const float* __restrict__ bs,
    const unsigned* __restrict__ wsu, float* __restrict__ out)
{
    __shared__ __align__(16) unsigned azpk[32 * 4];      // z pairs (kp0-15), a pairs (kp16-31)
    __shared__ __align__(16) unsigned hpk[2][100 * 4];   // packed h, double-buffered
    __shared__ __align__(16) float    hf[2][200 * 4];    // fp32 h (leak term), double-buffered
    __shared__ __align__(16) unsigned f1pk[100 * 4];
    __shared__ __align__(16) unsigned f2pk[100 * 4];

    const int t  = threadIdx.x;
    const int b0 = blockIdx.x * BT;

    const uint4* RUN4 = (const uint4*)(wsu + OFF_RUN4);
    const uint2* N2w  = (const uint2*)(wsu + OFF_N2);
    const uint2* W1w  = (const uint2*)(wsu + OFF_W1);
    const uint2* W2w  = (const uint2*)(wsu + OFF_W2);
    const uint2* MSw  = (const uint2*)(wsu + OFF_MS);

    // hoisted biases
    float brz = 0.f, buz = 0.f, bin = 0.f, bhn = 0.f, b1t = 0.f, b2t = 0.f, bms = 0.f;
    if (t < 200) {
        brz = b_ih[t] + b_hh[t];
        buz = b_ih[200 + t] + b_hh[200 + t];
        bin = b_ih[400 + t];
        bhn = b_hh[400 + t];
        b1t = b1[t];
        b2t = b2[t];
    }
    if (t < 64) bms = (t < 32) ? bm[t] : bs[t - 32];

    // ---- init state ----
    if (t < 200) {
        float hv[4];
        #pragma unroll
        for (int b = 0; b < 4; ++b) hv[b] = h0[(b0 + b) * 200 + t];
        ((float4*)hf[0])[t] = make_float4(hv[0], hv[1], hv[2], hv[3]);
        pack_store4(hpk[0], t >> 1, t & 1, hv[0], hv[1], hv[2], hv[3]);
    }
    if (t < 32) {
        float zv[4];
        #pragma unroll
        for (int b = 0; b < 4; ++b) zv[b] = z0[(b0 + b) * 32 + t];
        pack_store4(azpk, t >> 1, t & 1, zv[0], zv[1], zv[2], zv[3]);
    }
    // prefetch step-0 actions / eps
    float areg = 0.f;
    float ereg[4] = {0.f, 0.f, 0.f, 0.f};
    if (t < 128) {
        int b = t >> 5, j = t & 31;
        areg = actions[((b0 + b) * H_STEPS + 0) * 32 + j];
    }
    if (t < 32) {
        #pragma unroll
        for (int b = 0; b < 4; ++b) ereg[b] = eps[((b0 + b) * H_STEPS + 0) * 32 + t];
    }

    for (int step = 0; step < H_STEPS; ++step) {
        const int cur = step & 1, nxt = cur ^ 1;

        // write prefetched actions into azpk a-part
        if (t < 128) {
            int b = t >> 5, j = t & 31;
            unsigned lo = f2u16(areg);
            unsigned hi = (unsigned)__shfl_xor((int)lo, 1, 64);
            if (!(j & 1)) azpk[(16 + (j >> 1)) * 4 + b] = lo | (hi << 16);
        }
        __syncthreads();   // B1: azpk (z from prev sample, a), hpk[cur], hf[cur] ready

        const int sp = (step + 1 < H_STEPS) ? step + 1 : step;
        if (t < 128) {     // prefetch next actions (latency hides under GRU)
            int b = t >> 5, j = t & 31;
            areg = actions[((b0 + b) * H_STEPS + sp) * 32 + j];
        }

        // ---- GRU: thread t = feature t, dot over combined k via v_dot2_f32_f16 ----
        if (t < 200) {
            float ar[4]  = {0.f, 0.f, 0.f, 0.f};
            float au[4]  = {0.f, 0.f, 0.f, 0.f};
            float anx[4] = {0.f, 0.f, 0.f, 0.f};
            float anh[4] = {0.f, 0.f, 0.f, 0.f};
            const uint4* az4 = (const uint4*)azpk;
            const uint4* hc4 = (const uint4*)hpk[cur];

            #pragma unroll 4
            for (int g = 0; g < 16; ++g) {       // k = 0..63 (z,a)
                uint4 w  = RUN4[g * 200 + t];
                uint2 wn = N2w[g * 200 + t];
                uint4 xa = az4[2 * g], xb = az4[2 * g + 1];
                const unsigned* pa = (const unsigned*)&xa;
                const unsigned* pb = (const unsigned*)&xb;
                #pragma unroll
                for (int b = 0; b < 4; ++b) {
                    ar[b]  = dot2f(w.x,  pa[b], ar[b]);  ar[b]  = dot2f(w.y,  pb[b], ar[b]);
                    au[b]  = dot2f(w.z,  pa[b], au[b]);  au[b]  = dot2f(w.w,  pb[b], au[b]);
                    anx[b] = dot2f(wn.x, pa[b], anx[b]); anx[b] = dot2f(wn.y, pb[b], anx[b]);
                }
            }
            #pragma unroll 2
            for (int g = 16; g < 66; ++g) {      // k = 64..263 (h)
                uint4 w  = RUN4[g * 200 + t];
                uint2 wn = N2w[g * 200 + t];
                int lk = 2 * (g - 16);
                uint4 xa = hc4[lk], xb = hc4[lk + 1];
                const unsigned* pa = (const unsigned*)&xa;
                const unsigned* pb = (const unsigned*)&xb;
                #pragma unroll
                for (int b = 0; b < 4; ++b) {
                    ar[b]  = dot2f(w.x,  pa[b], ar[b]);  ar[b]  = dot2f(w.y,  pb[b], ar[b]);
                    au[b]  = dot2f(w.z,  pa[b], au[b]);  au[b]  = dot2f(w.w,  pb[b], au[b]);
                    anh[b] = dot2f(wn.x, pa[b], anh[b]); anh[b] = dot2f(wn.y, pb[b], anh[b]);
                }
            }
            const float4 ho4 = ((const float4*)hf[cur])[t];
            const float ho[4] = {ho4.x, ho4.y, ho4.z, ho4.w};
            float hn[4];
            const int obase = (b0 * H_STEPS + step) * OUT_FEAT + t;
            #pragma unroll
            for (int b = 0; b < 4; ++b) {
                float r = sigmoid_f(ar[b] + brz);
                float u = sigmoid_f(au[b] + buz);
                float n = tanh_f(anx[b] + bin + r * (anh[b] + bhn));
                hn[b] = (1.0f - u) * n + u * ho[b];
                out[obase + b * (H_STEPS * OUT_FEAT)] = hn[b];
            }
            ((float4*)hf[nxt])[t] = make_float4(hn[0], hn[1], hn[2], hn[3]);
            pack_store4(hpk[nxt], t >> 1, t & 1, hn[0], hn[1], hn[2], hn[3]);
        }
        __syncthreads();   // B2: h_new ready

        // ---- f1 = elu(h_new @ W1^T + b1) ----
        if (t < 200) {
            float acc[4] = {0.f, 0.f, 0.f, 0.f};
            const uint4* hv4 = (const uint4*)hpk[nxt];
            #pragma unroll 2
            for (int g = 0; g < 50; ++g) {
                uint2 w  = W1w[g * 200 + t];
                uint4 xa = hv4[2 * g], xb = hv4[2 * g + 1];
                const unsigned* pa = (const unsigned*)&xa;
                const unsigned* pb = (const unsigned*)&xb;
                #pragma unroll
                for (int b = 0; b < 4; ++b) {
                    acc[b] = dot2f(w.x, pa[b], acc[b]);
                    acc[b] = dot2f(w.y, pb[b], acc[b]);
                }
            }
            float r[4];
            #pragma unroll
            for (int b = 0; b < 4; ++b) {
                float v = acc[b] + b1t;
                r[b] = (v > 0.f) ? v : (__expf(v) - 1.0f);
            }
            pack_store4(f1pk, t >> 1, t & 1, r[0], r[1], r[2], r[3]);
        }
        __syncthreads();   // B3: f1 ready

        // ---- f2 = elu(f1 @ W2^T + b2) ----
        if (t < 200) {
            float acc[4] = {0.f, 0.f, 0.f, 0.f};
            const uint4* fv4 = (const uint4*)f1pk;
            #pragma unroll 2
            for (int g = 0; g < 50; ++g) {
                uint2 w  = W2w[g * 200 + t];
                uint4 xa = fv4[2 * g], xb = fv4[2 * g + 1];
                const unsigned* pa = (const unsigned*)&xa;
                const unsigned* pb = (const unsigned*)&xb;
                #pragma unroll
                for (int b = 0; b < 4; ++b) {
                    acc[b] = dot2f(w.x, pa[b], acc[b]);
                    acc[b] = dot2f(w.y, pb[b], acc[b]);
                }
            }
            float r[4];
            #pragma unroll
            for (int b = 0; b < 4; ++b) {
                float v = acc[b] + b2t;
                r[b] = (v > 0.f) ? v : (__expf(v) - 1.0f);
            }
            pack_store4(f2pk, t >> 1, t & 1, r[0], r[1], r[2], r[3]);
        }
        __syncthreads();   // B4: f2 ready

        // ---- heads (wave 0): mean / std + shfl exchange + sample ----
        if (t < 64) {
            float acc[4] = {0.f, 0.f, 0.f, 0.f};
            const uint4* fv4 = (const uint4*)f2pk;
            #pragma unroll 2
            for (int g = 0; g < 50; ++g) {
                uint2 w  = MSw[g * 64 + t];
                uint4 xa = fv4[2 * g], xb = fv4[2 * g + 1];
                const unsigned* pa = (const unsigned*)&xa;
                const unsigned* pb = (const unsigned*)&xb;
                #pragma unroll
                for (int b = 0; b < 4; ++b) {
                    acc[b] = dot2f(w.x, pa[b], acc[b]);
                    acc[b] = dot2f(w.y, pb[b], acc[b]);
                }
            }
            float v[4];
            if (t < 32) {
                #pragma unroll
                for (int b = 0; b < 4; ++b) v[b] = acc[b] + bms;               // mean
            } else {
                #pragma unroll
                for (int b = 0; b < 4; ++b) {
                    float ls = acc[b] + bms;
                    ls = fminf(fmaxf(ls, -10.0f), 2.0f);
                    v[b] = __expf(ls);                                          // std
                }
            }
            float sv[4];
            #pragma unroll
            for (int b = 0; b < 4; ++b) sv[b] = __shfl(v[b], (t & 31) + 32, 64);
            if (t < 32) {
                float zv[4];
                #pragma unroll
                for (int b = 0; b < 4; ++b) {
                    float z = v[b] + sv[b] * ereg[b];
                    zv[b] = z;
                    int base = ((b0 + b) * H_STEPS + step) * OUT_FEAT;
                    out[base + 200 + t] = z;
                    out[base + 232 + t] = v[b];
                }
                pack_store4(azpk, t >> 1, t & 1, zv[0], zv[1], zv[2], zv[3]);
            } else {
                #pragma unroll
                for (int b = 0; b < 4; ++b) {
                    int base = ((b0 + b) * H_STEPS + step) * OUT_FEAT;
                    out[base + 264 + (t - 32)] = v[b];
                }
            }
        }
        // prefetch next eps
        if (t < 32) {
            #pragma unroll
            for (int b = 0; b < 4; ++b)
                ereg[b] = eps[((b0 + b) * H_STEPS + sp) * 32 + t];
        }
        // loop: B1 covers azpk z-writes and the a-part write at top
    }
}

extern "C" void kernel_launch(void* const* d_in, const int* in_sizes, int n_in,
                              void* d_out, int out_size, void* d_ws, size_t ws_size,
                              hipStream_t stream) {
    const float* h0      = (const float*)d_in[0];
    const float* z0      = (const float*)d_in[1];
    const float* actions = (const float*)d_in[2];
    const float* eps     = (const float*)d_in[3];
    const float* W_ih    = (const float*)d_in[4];
    const float* b_ih    = (const float*)d_in[5];
    const float* W_hh    = (const float*)d_in[6];
    const float* b_hh    = (const float*)d_in[7];
    const float* W1      = (const float*)d_in[8];
    const float* b1      = (const float*)d_in[9];
    const float* W2      = (const float*)d_in[10];
    const float* b2      = (const float*)d_in[11];
    const float* Wm      = (const float*)d_in[12];
    const float* bm      = (const float*)d_in[13];
    const float* Ws      = (const float*)d_in[14];
    const float* bs      = (const float*)d_in[15];

    unsigned* ws = (unsigned*)d_ws;
    float* out = (float*)d_out;

    hipLaunchKernelGGL(pack_weights, dim3((WS_DW + 255) / 256), dim3(256), 0, stream,
                       W_ih, W_hh, W1, W2, Wm, Ws, ws);

    hipLaunchKernelGGL(rssm_rollout, dim3(B_TOT / BT), dim3(256), 0, stream,
                       h0, z0, actions, eps, b_ih, b_hh, b1, b2, bm, bs, ws, out);
}